// Round 2
// baseline (1698.087 us; speedup 1.0000x reference)
//
#include <hip/hip_runtime.h>
#include <hip/hip_bf16.h>
#include <math.h>

typedef __hip_bfloat16 bf16;
typedef __attribute__((ext_vector_type(8))) short short8;   // 8 bf16 (4 VGPRs)
typedef __attribute__((ext_vector_type(4))) float floatx4;  // 4 fp32 acc

#define B_  32
#define H_  168
#define N_  512
#define F_  8
#define P_  24
#define NF_ 4096
#define G4N 2048
#define M1  (B_*H_)   // 5376
#define NX  (B_*H_*N_*F_)  // 22020096

// ---------------- fp32 -> bf16 convert (x) ----------------------------------
__global__ __launch_bounds__(256) void cvt_f32_bf16(const float* __restrict__ in,
                                                    bf16* __restrict__ out, int n4) {
  int i = blockIdx.x * 256 + threadIdx.x;
  if (i < n4) {
    float4 v = ((const float4*)in)[i];
    bf16 o[4] = {__float2bfloat16(v.x), __float2bfloat16(v.y),
                 __float2bfloat16(v.z), __float2bfloat16(v.w)};
    *(ulong1*)(out + (size_t)i * 4) = *(ulong1*)o;
  }
}

// ---------- tiled transpose + convert: out[C,R](bf16) = in[R,C](f32)^T ------
__global__ __launch_bounds__(256) void transpose_cvt(const float* __restrict__ in,
                                                     bf16* __restrict__ out,
                                                     int R, int C) {
  __shared__ float t[32][33];
  int bx = blockIdx.x, by = blockIdx.y;
  int tx = threadIdx.x, ty = threadIdx.y;
#pragma unroll
  for (int yy = 0; yy < 32; yy += 8)
    t[ty + yy][tx] = in[(size_t)(by * 32 + ty + yy) * C + bx * 32 + tx];
  __syncthreads();
#pragma unroll
  for (int yy = 0; yy < 32; yy += 8)
    out[(size_t)(bx * 32 + ty + yy) * R + by * 32 + tx] =
        __float2bfloat16(t[tx][ty + yy]);
}

// ---------- transpose + add + convert: out = (in1+in2)^T in bf16 ------------
__global__ __launch_bounds__(256) void transpose_add_cvt(const float* __restrict__ in1,
                                                         const float* __restrict__ in2,
                                                         bf16* __restrict__ out,
                                                         int R, int C) {
  __shared__ float t[32][33];
  int bx = blockIdx.x, by = blockIdx.y;
  int tx = threadIdx.x, ty = threadIdx.y;
#pragma unroll
  for (int yy = 0; yy < 32; yy += 8) {
    size_t idx = (size_t)(by * 32 + ty + yy) * C + bx * 32 + tx;
    t[ty + yy][tx] = in1[idx] + in2[idx];
  }
  __syncthreads();
#pragma unroll
  for (int yy = 0; yy < 32; yy += 8)
    out[(size_t)(bx * 32 + ty + yy) * R + by * 32 + tx] =
        __float2bfloat16(t[tx][ty + yy]);
}

// ---------------- C[M,N] = A[M,K] @ BT[N,K]^T (+bias) -----------------------
// 128x128 tile, BK=32, 4 waves 2x2, 4x4 16x16x32 MFMA tiles per wave.
// OUT_BF16: store bf16, else fp32. bias is fp32 (or null).
template <bool OUT_BF16>
__global__ __launch_bounds__(256) void gemm_bt(const bf16* __restrict__ A,
                                               const bf16* __restrict__ BT,
                                               const float* __restrict__ bias,
                                               void* __restrict__ Cout,
                                               int M, int N, int K) {
  __shared__ short As[128 * 40];  // +8 pad vs 32: conflict-free, 16B aligned
  __shared__ short Bs[128 * 40];
  int tid  = threadIdx.x;
  int wave = tid >> 6, lane = tid & 63;
  int wm = wave >> 1, wn = wave & 1;
  int quad = lane >> 4, l16 = lane & 15;
  int m0 = blockIdx.y * 128, n0 = blockIdx.x * 128;

  floatx4 acc[4][4];
#pragma unroll
  for (int i = 0; i < 4; i++)
#pragma unroll
    for (int j = 0; j < 4; j++) acc[i][j] = (floatx4){0.f, 0.f, 0.f, 0.f};

  int r0 = tid >> 2;       // 0..63
  int c0 = (tid & 3) * 8;  // k-offset (elements)

  for (int k0 = 0; k0 < K; k0 += 32) {
    short8 a0 = *(const short8*)(A  + (size_t)(m0 + r0)      * K + k0 + c0);
    short8 a1 = *(const short8*)(A  + (size_t)(m0 + r0 + 64) * K + k0 + c0);
    short8 b0 = *(const short8*)(BT + (size_t)(n0 + r0)      * K + k0 + c0);
    short8 b1 = *(const short8*)(BT + (size_t)(n0 + r0 + 64) * K + k0 + c0);
    __syncthreads();
    *(short8*)(&As[r0 * 40 + c0])        = a0;
    *(short8*)(&As[(r0 + 64) * 40 + c0]) = a1;
    *(short8*)(&Bs[r0 * 40 + c0])        = b0;
    *(short8*)(&Bs[(r0 + 64) * 40 + c0]) = b1;
    __syncthreads();
    short8 af[4], bfr[4];
#pragma unroll
    for (int i = 0; i < 4; i++)
      af[i] = *(const short8*)(&As[(wm * 64 + i * 16 + l16) * 40 + quad * 8]);
#pragma unroll
    for (int j = 0; j < 4; j++)
      bfr[j] = *(const short8*)(&Bs[(wn * 64 + j * 16 + l16) * 40 + quad * 8]);
#pragma unroll
    for (int i = 0; i < 4; i++)
#pragma unroll
      for (int j = 0; j < 4; j++)
        acc[i][j] = __builtin_amdgcn_mfma_f32_16x16x32_bf16(af[i], bfr[j],
                                                            acc[i][j], 0, 0, 0);
  }
  // D layout: row = quad*4 + reg, col = lane&15 (verified)
#pragma unroll
  for (int i = 0; i < 4; i++) {
    int row = m0 + wm * 64 + i * 16 + quad * 4;
#pragma unroll
    for (int j = 0; j < 4; j++) {
      int col = n0 + wn * 64 + j * 16 + l16;
      float bv = bias ? bias[col] : 0.f;
#pragma unroll
      for (int r = 0; r < 4; r++) {
        float v = acc[i][j][r] + bv;
        if (OUT_BF16)
          ((bf16*)Cout)[(size_t)(row + r) * N + col] = __float2bfloat16(v);
        else
          ((float*)Cout)[(size_t)(row + r) * N + col] = v;
      }
    }
  }
}

// ---------------- one LSTM step ---------------------------------------------
// 64 WGs; WG g owns n in [g*8, g*8+8) -> 32 gate columns {gate*512+n}.
// 4 waves = 2x2 MFMA tiles over z [32 batches x 32 cols], K=512.
__global__ __launch_bounds__(256) void lstm_step(const bf16* __restrict__ h_in,
                                                 const bf16* __restrict__ WT,    // [2048,512]
                                                 const float* __restrict__ bvec, // [2048]
                                                 const float* __restrict__ xk_t, // [B, H*2048] slice, or null
                                                 float* __restrict__ c,
                                                 bf16* __restrict__ h_out,
                                                 bf16* __restrict__ pred_out) {  // or null
  int tid  = threadIdx.x;
  int wave = tid >> 6, lane = tid & 63;
  int tm = wave >> 1, tn = wave & 1;
  int quad = lane >> 4, l16 = lane & 15;
  int n0 = blockIdx.x * 8;
  int lc   = tn * 16 + l16;                    // local col 0..31
  int gcol = (lc >> 3) * 512 + n0 + (lc & 7);  // gate*512 + n

  floatx4 acc = (floatx4){0.f, 0.f, 0.f, 0.f};
  const bf16* ap = h_in + (size_t)(tm * 16 + l16) * 512 + quad * 8;
  const bf16* bp = WT + (size_t)gcol * 512 + quad * 8;
#pragma unroll
  for (int k0 = 0; k0 < 512; k0 += 32) {
    short8 av = *(const short8*)(ap + k0);
    short8 bv = *(const short8*)(bp + k0);
    acc = __builtin_amdgcn_mfma_f32_16x16x32_bf16(av, bv, acc, 0, 0, 0);
  }

  __shared__ float zs[32][33];
  float bias = bvec[gcol];
  int brow = tm * 16 + quad * 4;
#pragma unroll
  for (int r = 0; r < 4; r++) {
    float v = acc[r] + bias;
    if (xk_t) v += xk_t[(size_t)(brow + r) * (H_ * G4N) + gcol];
    zs[brow + r][lc] = v;
  }
  __syncthreads();

  int b = tid >> 3, j = tid & 7;  // 32 batches x 8 n-values
  int nn = n0 + j;
  float zi = zs[b][j], zf = zs[b][8 + j], zg = zs[b][16 + j], zo = zs[b][24 + j];
  float ig = 1.f / (1.f + expf(-zi));
  float fg = 1.f / (1.f + expf(-zf));
  float gg = tanhf(zg);
  float og = 1.f / (1.f + expf(-zo));
  float cn = fg * c[b * 512 + nn] + ig * gg;
  c[b * 512 + nn] = cn;
  float hn = og * tanhf(cn);
  h_out[b * 512 + nn] = __float2bfloat16(hn);
  if (pred_out) pred_out[(size_t)b * (P_ * N_) + nn] = __float2bfloat16(hn);
}

extern "C" void kernel_launch(void* const* d_in, const int* in_sizes, int n_in,
                              void* d_out, int out_size, void* d_ws, size_t ws_size,
                              hipStream_t stream) {
  const float* x       = (const float*)d_in[0];
  const float* conv_w  = (const float*)d_in[1];
  const float* conv_b  = (const float*)d_in[2];
  const float* lstm_k  = (const float*)d_in[3];
  const float* lstm_rk = (const float*)d_in[4];
  const float* lstm_b  = (const float*)d_in[5];
  const float* dense_w = (const float*)d_in[6];
  const float* dense_b = (const float*)d_in[7];
  float* out = (float*)d_out;

  char* p = (char*)d_ws;
  auto carve = [&](size_t bytes) {
    char* r = p;
    p += (bytes + 255) & ~(size_t)255;
    return r;
  };
  bf16*  xb    = (bf16*)carve((size_t)NX * 2);          // x in bf16 [5376,4096]
  bf16*  xr    = (bf16*)carve((size_t)M1 * N_ * 2);     // [5376,512]
  float* xk    = (float*)carve((size_t)M1 * G4N * 4);   // [5376,2048] fp32
  bf16*  cwT   = (bf16*)carve((size_t)N_ * NF_ * 2);    // [512,4096]
  bf16*  kT    = (bf16*)carve((size_t)G4N * N_ * 2);    // [2048,512]
  bf16*  rkT   = (bf16*)carve((size_t)G4N * N_ * 2);
  bf16*  wcT   = (bf16*)carve((size_t)G4N * N_ * 2);    // (k+rk)^T
  bf16*  dwT   = (bf16*)carve((size_t)N_ * N_ * 2);
  bf16*  preds = (bf16*)carve((size_t)B_ * P_ * N_ * 2);
  bf16*  hA    = (bf16*)carve((size_t)B_ * N_ * 2);
  bf16*  hB    = (bf16*)carve((size_t)B_ * N_ * 2);
  float* c     = (float*)carve((size_t)B_ * N_ * 4);

  cvt_f32_bf16<<<(NX / 4 + 255) / 256, 256, 0, stream>>>(x, xb, NX / 4);
  dim3 tb(32, 8);
  transpose_cvt<<<dim3(N_ / 32, NF_ / 32), tb, 0, stream>>>(conv_w, cwT, NF_, N_);
  transpose_cvt<<<dim3(G4N / 32, N_ / 32), tb, 0, stream>>>(lstm_k, kT, N_, G4N);
  transpose_cvt<<<dim3(G4N / 32, N_ / 32), tb, 0, stream>>>(lstm_rk, rkT, N_, G4N);
  transpose_add_cvt<<<dim3(G4N / 32, N_ / 32), tb, 0, stream>>>(lstm_k, lstm_rk, wcT,
                                                                N_, G4N);
  transpose_cvt<<<dim3(N_ / 32, N_ / 32), tb, 0, stream>>>(dense_w, dwT, N_, N_);
  hipMemsetAsync(hA, 0, (size_t)B_ * N_ * 2, stream);
  hipMemsetAsync(c, 0, (size_t)B_ * N_ * 4, stream);

  // xr = x @ conv_w + conv_b   [5376,4096]x[4096,512] -> bf16
  gemm_bt<true><<<dim3(N_ / 128, M1 / 128), 256, 0, stream>>>(xb, cwT, conv_b, xr,
                                                              M1, N_, NF_);
  // xk = xr @ lstm_k           [5376,512]x[512,2048] -> fp32
  gemm_bt<false><<<dim3(G4N / 128, M1 / 128), 256, 0, stream>>>(xr, kT, nullptr, xk,
                                                                M1, G4N, N_);

  bf16* hbuf[2] = {hA, hB};
  for (int t = 0; t < H_; ++t)
    lstm_step<<<64, 256, 0, stream>>>(hbuf[t & 1], rkT, lstm_b,
                                      xk + (size_t)t * G4N, c,
                                      hbuf[(t + 1) & 1], (bf16*)nullptr);
  for (int ps = 0; ps < P_; ++ps) {
    int s = H_ + ps;
    lstm_step<<<64, 256, 0, stream>>>(hbuf[s & 1], wcT, lstm_b,
                                      (const float*)nullptr, c,
                                      hbuf[(s + 1) & 1], preds + (size_t)ps * N_);
  }
  // out = preds @ dense_w + dense_b   [768,512]x[512,512] -> fp32
  gemm_bt<false><<<dim3(N_ / 128, (B_ * P_) / 128), 256, 0, stream>>>(
      preds, dwT, dense_b, out, B_ * P_, N_, N_);
}